// Round 2
// baseline (626.570 us; speedup 1.0000x reference)
//
#include <hip/hip_runtime.h>

// ---------------------------------------------------------------------------
// MHA with softmax over the HEADS axis (torch legacy F.softmax dim=1).
// B=2, S=2048, D=1024, H=16, dh=64. scale = sqrt(1024) = 32.
//
// Pipeline (round 2: barrier-free attention via two-pass Z):
//  1. convert_x : queries/keys/values f32 -> bf16          (ws Xb, 24 MB)
//  2. transpose_w: Wq,Wk,Wv,Wo f32 [K][N] -> bf16 Wt [N][K] (ws Wt, 8 MB)
//  3. gemm<0> x2: Qb, Kb = X @ W + b   (bf16 [4096][1024])
//     gemm<1>   : Vt = (Xv @ Wv + bv)^T per batch (bf16 [2][1024][2048])
//  4. zsum      : rz[b][q][k] = bf16( 1 / sum_h exp(S_h/32) ), all 16 heads
//                 per wave in-register. No LDS/atomics/barriers.
//  5. pv        : per (qtile16, b, head): recompute S, w = exp*rz, O += w@V.
//                 No LDS/barriers; heads decoupled; writes Ob directly.
//  6. gemm<2>   : out = Ob @ Wo + bo (f32)
// ws layout (56 MB): [Xb 12M ushorts | Wt 4M | Qb 4M | Kb 4M | Vt 4M]
// Zinv (8M ushorts) aliases Xb[0:8M]; Ob (4M) aliases Xb[8M:12M] (X dead).
// ---------------------------------------------------------------------------

typedef unsigned short ushort;
typedef __attribute__((ext_vector_type(8))) short short8;
typedef __attribute__((ext_vector_type(4))) short short4v;
typedef __attribute__((ext_vector_type(4))) float f32x4;
typedef __attribute__((ext_vector_type(4))) float float4v;
typedef __attribute__((ext_vector_type(4))) unsigned int uint4v;
typedef __attribute__((ext_vector_type(2))) unsigned int uint2v;

#define MFMA32(a, b, c) __builtin_amdgcn_mfma_f32_16x16x32_bf16(a, b, c, 0, 0, 0)
#define MFMA16(a, b, c) __builtin_amdgcn_mfma_f32_16x16x16bf16_1k(a, b, c, 0, 0, 0)

__device__ __forceinline__ ushort f2bf(float f) {  // round-to-nearest-even
    unsigned u = __float_as_uint(f);
    u += 0x7fffu + ((u >> 16) & 1u);
    return (ushort)(u >> 16);
}
__device__ __forceinline__ float bf2f(ushort u) {
    return __uint_as_float(((unsigned)u) << 16);
}

// ------------------------- 1. convert inputs to bf16 -----------------------
__global__ __launch_bounds__(256) void convert_x_kernel(
    const float* __restrict__ q, const float* __restrict__ k,
    const float* __restrict__ v, ushort* __restrict__ out) {
    const size_t NPER = 4194304ull;  // 4096*1024
    size_t idx = ((size_t)blockIdx.x * 256 + threadIdx.x) * 8;
    const size_t stride = (size_t)gridDim.x * 256 * 8;
    for (; idx < 3 * NPER; idx += stride) {
        const float* src;
        size_t off;
        if (idx < NPER)          { src = q; off = idx; }
        else if (idx < 2 * NPER) { src = k; off = idx - NPER; }
        else                     { src = v; off = idx - 2 * NPER; }
        float4v a = *(const float4v*)(src + off);
        float4v b = *(const float4v*)(src + off + 4);
        union { ushort u[8]; uint4v v4; } pk;
        #pragma unroll
        for (int j = 0; j < 4; j++) { pk.u[j] = f2bf(a[j]); pk.u[4 + j] = f2bf(b[j]); }
        *(uint4v*)(out + idx) = pk.v4;
    }
}

// ------------------- 2. transpose weights: [K][N] -> [N][K] bf16 -----------
__global__ __launch_bounds__(256) void transpose_w_kernel(
    const float* __restrict__ w0, const float* __restrict__ w1,
    const float* __restrict__ w2, const float* __restrict__ w3,
    ushort* __restrict__ Wt) {
    const float* W = blockIdx.z == 0 ? w0 : blockIdx.z == 1 ? w1 : blockIdx.z == 2 ? w2 : w3;
    ushort* out = Wt + (size_t)blockIdx.z * 1024 * 1024;
    __shared__ ushort st[64 * 72];
    int t = threadIdx.x;
    int kb = blockIdx.y * 64, nb = blockIdx.x * 64;
    int c4 = (t & 15) * 4;  // n offset within tile
    int r0 = t >> 4;
    #pragma unroll
    for (int p = 0; p < 4; p++) {
        int r = r0 + p * 16;  // k row within tile
        float4v f = *(const float4v*)(W + (size_t)(kb + r) * 1024 + nb + c4);
        union { ushort u[4]; uint2v v2; } pk;
        #pragma unroll
        for (int j = 0; j < 4; j++) pk.u[j] = f2bf(f[j]);
        *(uint2v*)(st + r * 72 + c4) = pk.v2;
    }
    __syncthreads();
    int n = t >> 2;
    int kc = (t & 3) * 16;
    union { ushort u[16]; uint4v v4[2]; } tw;
    #pragma unroll
    for (int j = 0; j < 16; j++) tw.u[j] = st[(kc + j) * 72 + n];
    uint4v* dst = (uint4v*)(out + (size_t)(nb + n) * 1024 + kb + kc);
    dst[0] = tw.v4[0];
    dst[1] = tw.v4[1];
}

// ------------------- 3./6. GEMM: C[M=4096][N=1024] = A[M][1024] * Bt[N][1024]^T
// MODE 0: bf16 row-major out.  MODE 1: bf16 transposed per batch (Vt[b][n][m]).
// MODE 2: f32 out + bias.  LDS XOR-swizzled (stride-128B tiles -> 2-way max).
template <int MODE>
__global__ __launch_bounds__(256, 2) void gemm_bt_kernel(
    const ushort* __restrict__ A, const ushort* __restrict__ Bt,
    const float* __restrict__ bias, ushort* __restrict__ Cb,
    float* __restrict__ Cf) {
    __shared__ ushort sA[128 * 64];
    __shared__ ushort sB[128 * 64];
    int tid = threadIdx.x, lane = tid & 63, wave = tid >> 6;
    int li = lane & 15, g = lane >> 4;
    int mt = blockIdx.y * 128, nt = blockIdx.x * 128;
    int wm = (wave >> 1) * 64, wn = (wave & 1) * 64;
    f32x4 acc[4][4] = {};
    for (int k0 = 0; k0 < 1024; k0 += 64) {
        #pragma unroll
        for (int i = 0; i < 4; i++) {
            int c = tid + i * 256;          // 0..1023 chunk id (16B chunks)
            int row = c >> 3, colb = (c & 7) * 16;
            int sw = colb ^ ((row & 7) << 4);
            *(uint4v*)((char*)sA + row * 128 + sw) =
                *(const uint4v*)(A + (size_t)(mt + row) * 1024 + k0 + (colb >> 1));
            *(uint4v*)((char*)sB + row * 128 + sw) =
                *(const uint4v*)(Bt + (size_t)(nt + row) * 1024 + k0 + (colb >> 1));
        }
        __syncthreads();
        #pragma unroll
        for (int kk = 0; kk < 2; kk++) {
            short8 af[4], bfr[4];
            #pragma unroll
            for (int i = 0; i < 4; i++) {
                int ra = wm + i * 16 + li;
                int cb = kk * 64 + g * 16;
                af[i] = *(const short8*)((char*)sA + ra * 128 + (cb ^ ((ra & 7) << 4)));
                int rb = wn + i * 16 + li;
                bfr[i] = *(const short8*)((char*)sB + rb * 128 + (cb ^ ((rb & 7) << 4)));
            }
            #pragma unroll
            for (int mi = 0; mi < 4; mi++)
                #pragma unroll
                for (int ni = 0; ni < 4; ni++)
                    acc[mi][ni] = MFMA32(af[mi], bfr[ni], acc[mi][ni]);
        }
        __syncthreads();
    }
    // epilogue: C tile layout col = lane&15 (n), row = g*4 + r (m)
    #pragma unroll
    for (int mi = 0; mi < 4; mi++) {
        #pragma unroll
        for (int ni = 0; ni < 4; ni++) {
            int n = nt + wn + ni * 16 + li;
            int m0 = mt + wm + mi * 16 + g * 4;
            float bv = bias[n];
            if (MODE == 0) {
                #pragma unroll
                for (int r = 0; r < 4; r++)
                    Cb[(size_t)(m0 + r) * 1024 + n] = f2bf(acc[mi][ni][r] + bv);
            } else if (MODE == 1) {
                int batch = m0 >> 11, mm = m0 & 2047;
                union { ushort u[4]; uint2v v2; } pk;
                #pragma unroll
                for (int r = 0; r < 4; r++) pk.u[r] = f2bf(acc[mi][ni][r] + bv);
                *(uint2v*)(Cb + (size_t)batch * 1024 * 2048 + (size_t)n * 2048 + mm) = pk.v2;
            } else {
                #pragma unroll
                for (int r = 0; r < 4; r++)
                    Cf[(size_t)(m0 + r) * 1024 + n] = acc[mi][ni][r] + bv;
            }
        }
    }
}

// ------------------- 4. zsum: rz[b][q][k] = 1/sum_h exp(S/32), bf16 --------
// grid (64 qtiles, 16 kgroups, 2 b), 256 thr = 4 waves. Wave = 32q x 32k tile,
// loops 16 heads in-register. No LDS, no atomics, no barriers.
__global__ __launch_bounds__(256, 4) void zsum_kernel(
    const ushort* __restrict__ Qb, const ushort* __restrict__ Kb,
    ushort* __restrict__ Zinv) {
    int tid = threadIdx.x, lane = tid & 63, wave = tid >> 6;
    int li = lane & 15, g = lane >> 4;
    int b = blockIdx.z;
    int q0 = blockIdx.x * 32;
    int k0 = blockIdx.y * 128 + wave * 32;
    const ushort* Qp = Qb + (size_t)(b * 2048 + q0) * 1024 + g * 8;
    const ushort* Kp = Kb + (size_t)(b * 2048 + k0) * 1024 + g * 8;
    f32x4 zacc[2][2] = {};  // [qs][ks], vector lane = r
    for (int h = 0; h < 16; h++) {
        int co = h * 64;
        short8 qf[2][2], kf[2][2];
        #pragma unroll
        for (int qs = 0; qs < 2; qs++)
            #pragma unroll
            for (int dc = 0; dc < 2; dc++)
                qf[qs][dc] = *(const short8*)(Qp + (size_t)(qs * 16 + li) * 1024 + co + dc * 32);
        #pragma unroll
        for (int ks = 0; ks < 2; ks++)
            #pragma unroll
            for (int dc = 0; dc < 2; dc++)
                kf[ks][dc] = *(const short8*)(Kp + (size_t)(ks * 16 + li) * 1024 + co + dc * 32);
        #pragma unroll
        for (int qs = 0; qs < 2; qs++)
            #pragma unroll
            for (int ks = 0; ks < 2; ks++) {
                f32x4 st = {0.f, 0.f, 0.f, 0.f};
                st = MFMA32(kf[ks][0], qf[qs][0], st);
                st = MFMA32(kf[ks][1], qf[qs][1], st);
                #pragma unroll
                for (int r = 0; r < 4; r++)
                    zacc[qs][ks][r] += __expf(st[r] * 0.03125f);
            }
    }
    #pragma unroll
    for (int qs = 0; qs < 2; qs++)
        #pragma unroll
        for (int ks = 0; ks < 2; ks++) {
            union { ushort u[4]; uint2v v; } pk;
            #pragma unroll
            for (int r = 0; r < 4; r++)
                pk.u[r] = f2bf(__builtin_amdgcn_rcpf(zacc[qs][ks][r]));
            *(uint2v*)(Zinv + (size_t)(b * 2048 + q0 + qs * 16 + li) * 2048 +
                       k0 + ks * 16 + g * 4) = pk.v;
        }
}

// ------------------- 5. pv: recompute S, weights = exp*rz, O += w@V --------
// grid (32 qgroups, 2 b, 16 heads), 256 thr = 4 waves; wave = 16q x 1 head,
// full k loop. Waves in a block share the head's K/V column slice (L2 reuse).
// No LDS, no barriers. Heads write disjoint Ob columns (no partials).
__global__ __launch_bounds__(256, 4) void pv_kernel(
    const ushort* __restrict__ Qb, const ushort* __restrict__ Kb,
    const ushort* __restrict__ Vt, const ushort* __restrict__ Zinv,
    ushort* __restrict__ Ob) {
    int tid = threadIdx.x, lane = tid & 63, wave = tid >> 6;
    int li = lane & 15, g = lane >> 4;
    int b = blockIdx.y, h = blockIdx.z;
    int q0 = blockIdx.x * 64 + wave * 16;
    const ushort* Qp = Qb + (size_t)(b * 2048 + q0 + li) * 1024 + h * 64 + g * 8;
    short8 qf0 = *(const short8*)(Qp);
    short8 qf1 = *(const short8*)(Qp + 32);
    const ushort* Kp = Kb + (size_t)b * 2048 * 1024 + h * 64 + g * 8;
    const ushort* Vp = Vt + (size_t)(b * 1024 + h * 64 + li) * 2048;
    const ushort* Zp = Zinv + (size_t)(b * 2048 + q0 + li) * 2048;
    f32x4 oacc[4] = {};  // [ds], vector lane = r -> q row g*4+r
    for (int kb = 0; kb < 2048; kb += 32) {
        short8 kf00 = *(const short8*)(Kp + (size_t)(kb + li) * 1024);
        short8 kf01 = *(const short8*)(Kp + (size_t)(kb + li) * 1024 + 32);
        short8 kf10 = *(const short8*)(Kp + (size_t)(kb + 16 + li) * 1024);
        short8 kf11 = *(const short8*)(Kp + (size_t)(kb + 16 + li) * 1024 + 32);
        f32x4 st0 = {0.f, 0.f, 0.f, 0.f}, st1 = {0.f, 0.f, 0.f, 0.f};
        st0 = MFMA32(kf00, qf0, st0);
        st0 = MFMA32(kf01, qf1, st0);
        st1 = MFMA32(kf10, qf0, st1);
        st1 = MFMA32(kf11, qf1, st1);
        union { ushort u[4]; uint2v v; } rz0, rz1;
        rz0.v = *(const uint2v*)(Zp + kb + g * 4);
        rz1.v = *(const uint2v*)(Zp + kb + 16 + g * 4);
        short4v pf0, pf1;
        #pragma unroll
        for (int r = 0; r < 4; r++) {
            pf0[r] = (short)f2bf(__expf(st0[r] * 0.03125f) * bf2f(rz0.u[r]));
            pf1[r] = (short)f2bf(__expf(st1[r] * 0.03125f) * bf2f(rz1.u[r]));
        }
        #pragma unroll
        for (int ds = 0; ds < 4; ds++) {
            short4v vf0 = *(const short4v*)(Vp + (size_t)(ds * 16) * 2048 + kb + g * 4);
            short4v vf1 = *(const short4v*)(Vp + (size_t)(ds * 16) * 2048 + kb + 16 + g * 4);
            oacc[ds] = MFMA16(pf0, vf0, oacc[ds]);
            oacc[ds] = MFMA16(pf1, vf1, oacc[ds]);
        }
    }
    ushort* Oo = Ob + (size_t)(b * 2048 + q0) * 1024 + h * 64;
    #pragma unroll
    for (int ds = 0; ds < 4; ds++)
        #pragma unroll
        for (int r = 0; r < 4; r++)
            Oo[(size_t)(g * 4 + r) * 1024 + ds * 16 + li] = f2bf(oacc[ds][r]);
}

// ---------------------------------------------------------------------------
extern "C" void kernel_launch(void* const* d_in, const int* in_sizes, int n_in,
                              void* d_out, int out_size, void* d_ws, size_t ws_size,
                              hipStream_t stream) {
    const float* queries = (const float*)d_in[0];
    const float* keys    = (const float*)d_in[1];
    const float* values  = (const float*)d_in[2];
    const float* Wq = (const float*)d_in[3];
    const float* bq = (const float*)d_in[4];
    const float* Wk = (const float*)d_in[5];
    const float* bk = (const float*)d_in[6];
    const float* Wv = (const float*)d_in[7];
    const float* bv = (const float*)d_in[8];
    const float* Wo = (const float*)d_in[9];
    const float* bo = (const float*)d_in[10];
    float* out = (float*)d_out;

    // ws layout (ushort units). Requires ws_size >= 56 MB.
    ushort* Xb  = (ushort*)d_ws;            // [3][4096][1024]   (12M u)
    ushort* Wt  = Xb + 12ull * 1024 * 1024; // [4][1024][1024]   (4M u)
    ushort* Qb  = Wt + 4ull * 1024 * 1024;  // [4096][1024]      (4M u)
    ushort* Kb  = Qb + 4ull * 1024 * 1024;  // [4096][1024]      (4M u)
    ushort* Vtb = Kb + 4ull * 1024 * 1024;  // [2][1024][2048]   (4M u)
    // After projections Xb is dead: Zinv (8M u) and Ob (4M u) alias it.
    ushort* Zinv = Xb;                       // [2][2048][2048] bf16 (8M u)
    ushort* Ob   = Xb + 8ull * 1024 * 1024;  // [4096][1024]        (4M u)

    convert_x_kernel<<<2048, 256, 0, stream>>>(queries, keys, values, Xb);
    transpose_w_kernel<<<dim3(16, 16, 4), 256, 0, stream>>>(Wq, Wk, Wv, Wo, Wt);
    gemm_bt_kernel<0><<<dim3(8, 32), 256, 0, stream>>>(
        Xb, Wt, bq, Qb, nullptr);
    gemm_bt_kernel<0><<<dim3(8, 32), 256, 0, stream>>>(
        Xb + 4ull * 1024 * 1024, Wt + 1ull * 1024 * 1024, bk, Kb, nullptr);
    gemm_bt_kernel<1><<<dim3(8, 32), 256, 0, stream>>>(
        Xb + 8ull * 1024 * 1024, Wt + 2ull * 1024 * 1024, bv, Vtb, nullptr);
    zsum_kernel<<<dim3(64, 16, 2), 256, 0, stream>>>(Qb, Kb, Zinv);
    pv_kernel<<<dim3(32, 2, 16), 256, 0, stream>>>(Qb, Kb, Vtb, Zinv, Ob);
    gemm_bt_kernel<2><<<dim3(8, 32), 256, 0, stream>>>(
        Ob, Wt + 3ull * 1024 * 1024, bo, nullptr, out);
}

// Round 3
// 241.845 us; speedup vs baseline: 2.5908x; 2.5908x over previous
//
#include <hip/hip_runtime.h>

// ---------------------------------------------------------------------------
// MHA with softmax over the HEADS axis (torch legacy F.softmax dim=1).
// B=2, S=2048, D=1024, H=16, dh=64. scale = sqrt(1024) = 32.
//
// Round 3: LDS-staged, coalesced attention kernels (two-pass Z kept).
//  4. zsum : rz[b][q][k] = bf16(1/sum_h exp(S/32)); block 32q x 128k, per-head
//            Q/K tiles staged into XOR-swizzled LDS (coalesced), frags via
//            ds_read_b128. No atomics.
//  5. pv   : block 64q x 2heads; per 32-k step stage K (swizzled) + V,Z
//            (padded rows) into LDS; recompute S, w = exp*rz, O += w@V.
// ws layout (56 MB): [Xb 12M ushorts | Wt 4M | Qb 4M | Kb 4M | Vt 4M]
// Zinv (8M ushorts) aliases Xb[0:8M]; Ob (4M) aliases Xb[8M:12M] (X dead).
// ---------------------------------------------------------------------------

typedef unsigned short ushort;
typedef __attribute__((ext_vector_type(8))) short short8;
typedef __attribute__((ext_vector_type(4))) short short4v;
typedef __attribute__((ext_vector_type(4))) float f32x4;
typedef __attribute__((ext_vector_type(4))) float float4v;
typedef __attribute__((ext_vector_type(4))) unsigned int uint4v;
typedef __attribute__((ext_vector_type(2))) unsigned int uint2v;

#define MFMA32(a, b, c) __builtin_amdgcn_mfma_f32_16x16x32_bf16(a, b, c, 0, 0, 0)
#define MFMA16(a, b, c) __builtin_amdgcn_mfma_f32_16x16x16bf16_1k(a, b, c, 0, 0, 0)

__device__ __forceinline__ ushort f2bf(float f) {  // round-to-nearest-even
    unsigned u = __float_as_uint(f);
    u += 0x7fffu + ((u >> 16) & 1u);
    return (ushort)(u >> 16);
}
__device__ __forceinline__ float bf2f(ushort u) {
    return __uint_as_float(((unsigned)u) << 16);
}

// ------------------------- 1. convert inputs to bf16 -----------------------
__global__ __launch_bounds__(256) void convert_x_kernel(
    const float* __restrict__ q, const float* __restrict__ k,
    const float* __restrict__ v, ushort* __restrict__ out) {
    const size_t NPER = 4194304ull;  // 4096*1024
    size_t idx = ((size_t)blockIdx.x * 256 + threadIdx.x) * 8;
    const size_t stride = (size_t)gridDim.x * 256 * 8;
    for (; idx < 3 * NPER; idx += stride) {
        const float* src;
        size_t off;
        if (idx < NPER)          { src = q; off = idx; }
        else if (idx < 2 * NPER) { src = k; off = idx - NPER; }
        else                     { src = v; off = idx - 2 * NPER; }
        float4v a = *(const float4v*)(src + off);
        float4v b = *(const float4v*)(src + off + 4);
        union { ushort u[8]; uint4v v4; } pk;
        #pragma unroll
        for (int j = 0; j < 4; j++) { pk.u[j] = f2bf(a[j]); pk.u[4 + j] = f2bf(b[j]); }
        *(uint4v*)(out + idx) = pk.v4;
    }
}

// ------------------- 2. transpose weights: [K][N] -> [N][K] bf16 -----------
__global__ __launch_bounds__(256) void transpose_w_kernel(
    const float* __restrict__ w0, const float* __restrict__ w1,
    const float* __restrict__ w2, const float* __restrict__ w3,
    ushort* __restrict__ Wt) {
    const float* W = blockIdx.z == 0 ? w0 : blockIdx.z == 1 ? w1 : blockIdx.z == 2 ? w2 : w3;
    ushort* out = Wt + (size_t)blockIdx.z * 1024 * 1024;
    __shared__ ushort st[64 * 72];
    int t = threadIdx.x;
    int kb = blockIdx.y * 64, nb = blockIdx.x * 64;
    int c4 = (t & 15) * 4;  // n offset within tile
    int r0 = t >> 4;
    #pragma unroll
    for (int p = 0; p < 4; p++) {
        int r = r0 + p * 16;  // k row within tile
        float4v f = *(const float4v*)(W + (size_t)(kb + r) * 1024 + nb + c4);
        union { ushort u[4]; uint2v v2; } pk;
        #pragma unroll
        for (int j = 0; j < 4; j++) pk.u[j] = f2bf(f[j]);
        *(uint2v*)(st + r * 72 + c4) = pk.v2;
    }
    __syncthreads();
    int n = t >> 2;
    int kc = (t & 3) * 16;
    union { ushort u[16]; uint4v v4[2]; } tw;
    #pragma unroll
    for (int j = 0; j < 16; j++) tw.u[j] = st[(kc + j) * 72 + n];
    uint4v* dst = (uint4v*)(out + (size_t)(nb + n) * 1024 + kb + kc);
    dst[0] = tw.v4[0];
    dst[1] = tw.v4[1];
}

// ------------------- 3./6. GEMM: C[M=4096][N=1024] = A[M][1024] * Bt[N][1024]^T
template <int MODE>
__global__ __launch_bounds__(256, 2) void gemm_bt_kernel(
    const ushort* __restrict__ A, const ushort* __restrict__ Bt,
    const float* __restrict__ bias, ushort* __restrict__ Cb,
    float* __restrict__ Cf) {
    __shared__ ushort sA[128 * 64];
    __shared__ ushort sB[128 * 64];
    int tid = threadIdx.x, lane = tid & 63, wave = tid >> 6;
    int li = lane & 15, g = lane >> 4;
    int mt = blockIdx.y * 128, nt = blockIdx.x * 128;
    int wm = (wave >> 1) * 64, wn = (wave & 1) * 64;
    f32x4 acc[4][4] = {};
    for (int k0 = 0; k0 < 1024; k0 += 64) {
        #pragma unroll
        for (int i = 0; i < 4; i++) {
            int c = tid + i * 256;          // 0..1023 chunk id (16B chunks)
            int row = c >> 3, colb = (c & 7) * 16;
            int sw = colb ^ ((row & 7) << 4);
            *(uint4v*)((char*)sA + row * 128 + sw) =
                *(const uint4v*)(A + (size_t)(mt + row) * 1024 + k0 + (colb >> 1));
            *(uint4v*)((char*)sB + row * 128 + sw) =
                *(const uint4v*)(Bt + (size_t)(nt + row) * 1024 + k0 + (colb >> 1));
        }
        __syncthreads();
        #pragma unroll
        for (int kk = 0; kk < 2; kk++) {
            short8 af[4], bfr[4];
            #pragma unroll
            for (int i = 0; i < 4; i++) {
                int ra = wm + i * 16 + li;
                int cb = kk * 64 + g * 16;
                af[i] = *(const short8*)((char*)sA + ra * 128 + (cb ^ ((ra & 7) << 4)));
                int rb = wn + i * 16 + li;
                bfr[i] = *(const short8*)((char*)sB + rb * 128 + (cb ^ ((rb & 7) << 4)));
            }
            #pragma unroll
            for (int mi = 0; mi < 4; mi++)
                #pragma unroll
                for (int ni = 0; ni < 4; ni++)
                    acc[mi][ni] = MFMA32(af[mi], bfr[ni], acc[mi][ni]);
        }
        __syncthreads();
    }
    #pragma unroll
    for (int mi = 0; mi < 4; mi++) {
        #pragma unroll
        for (int ni = 0; ni < 4; ni++) {
            int n = nt + wn + ni * 16 + li;
            int m0 = mt + wm + mi * 16 + g * 4;
            float bv = bias[n];
            if (MODE == 0) {
                #pragma unroll
                for (int r = 0; r < 4; r++)
                    Cb[(size_t)(m0 + r) * 1024 + n] = f2bf(acc[mi][ni][r] + bv);
            } else if (MODE == 1) {
                int batch = m0 >> 11, mm = m0 & 2047;
                union { ushort u[4]; uint2v v2; } pk;
                #pragma unroll
                for (int r = 0; r < 4; r++) pk.u[r] = f2bf(acc[mi][ni][r] + bv);
                *(uint2v*)(Cb + (size_t)batch * 1024 * 2048 + (size_t)n * 2048 + mm) = pk.v2;
            } else {
                #pragma unroll
                for (int r = 0; r < 4; r++)
                    Cf[(size_t)(m0 + r) * 1024 + n] = acc[mi][ni][r] + bv;
            }
        }
    }
}

// ------------------- 4. zsum v2: LDS-staged, coalesced ---------------------
// grid (64 qt, 16 kg, 2 b), 256 thr = 4 waves. Block = 32q x 128k; wave owns
// 32k. Per head: stage Q[32][64] + K[128][64] (XOR-swizzled rows of 128B).
__global__ __launch_bounds__(256, 4) void zsum_kernel(
    const ushort* __restrict__ Qb, const ushort* __restrict__ Kb,
    ushort* __restrict__ Zinv) {
    __shared__ ushort sQ[32 * 64];   // 4 KB, swizzled
    __shared__ ushort sK[128 * 64];  // 16 KB, swizzled
    int tid = threadIdx.x, lane = tid & 63, wave = tid >> 6;
    int li = lane & 15, g = lane >> 4;
    int b = blockIdx.z;
    int q0 = blockIdx.x * 32;
    int k0 = blockIdx.y * 128;
    const ushort* Qp = Qb + (size_t)(b * 2048 + q0) * 1024;
    const ushort* Kp = Kb + (size_t)(b * 2048 + k0) * 1024;
    int srow = tid >> 3, sch = tid & 7;   // Q staging: 32 rows x 8 chunks
    f32x4 zacc[2][2] = {};
    for (int h = 0; h < 16; h++) {
        int co = h * 64;
        __syncthreads();
        {   // stage Q tile (coalesced: 8 consecutive threads = one 128B row)
            int sw = (sch * 16) ^ ((srow & 7) << 4);
            *(uint4v*)((char*)sQ + (srow & 31) * 128 + sw) =
                *(const uint4v*)(Qp + (size_t)(srow & 31) * 1024 + co + sch * 8);
        }
        #pragma unroll
        for (int i = 0; i < 4; i++) {  // stage K tile: 128 rows x 8 chunks
            int c = tid + i * 256;
            int r = c >> 3, ch = c & 7;
            int sw = (ch * 16) ^ ((r & 7) << 4);
            *(uint4v*)((char*)sK + r * 128 + sw) =
                *(const uint4v*)(Kp + (size_t)r * 1024 + co + ch * 8);
        }
        __syncthreads();
        short8 qf[2][2], kf[2][2];
        #pragma unroll
        for (int qs = 0; qs < 2; qs++)
            #pragma unroll
            for (int dc = 0; dc < 2; dc++) {
                int row = qs * 16 + li;
                qf[qs][dc] = *(const short8*)(
                    (char*)sQ + row * 128 + ((dc * 64 + g * 16) ^ ((row & 7) << 4)));
            }
        #pragma unroll
        for (int ks = 0; ks < 2; ks++)
            #pragma unroll
            for (int dc = 0; dc < 2; dc++) {
                int row = wave * 32 + ks * 16 + li;
                kf[ks][dc] = *(const short8*)(
                    (char*)sK + row * 128 + ((dc * 64 + g * 16) ^ ((row & 7) << 4)));
            }
        #pragma unroll
        for (int qs = 0; qs < 2; qs++)
            #pragma unroll
            for (int ks = 0; ks < 2; ks++) {
                f32x4 st = {0.f, 0.f, 0.f, 0.f};
                st = MFMA32(kf[ks][0], qf[qs][0], st);
                st = MFMA32(kf[ks][1], qf[qs][1], st);
                #pragma unroll
                for (int r = 0; r < 4; r++)
                    zacc[qs][ks][r] += __expf(st[r] * 0.03125f);
            }
    }
    #pragma unroll
    for (int qs = 0; qs < 2; qs++)
        #pragma unroll
        for (int ks = 0; ks < 2; ks++) {
            union { ushort u[4]; uint2v v; } pk;
            #pragma unroll
            for (int r = 0; r < 4; r++)
                pk.u[r] = f2bf(__builtin_amdgcn_rcpf(zacc[qs][ks][r]));
            *(uint2v*)(Zinv + (size_t)(b * 2048 + q0 + qs * 16 + li) * 2048 +
                       k0 + wave * 32 + ks * 16 + g * 4) = pk.v;
        }
}

// ------------------- 5. pv v2: LDS-staged, coalesced -----------------------
// grid (32 qt, 2 b, 8 hp), 256 thr = 4 waves. Block = 64q x 2 heads; wave =
// 32q x 1 head. Per 32-k step: stage K (swizzled), V and Z (rows padded to
// 80B -> <=2-way banks), then frags via ds_read. Fragment flow identical to
// the verified round-2 kernel.
__global__ __launch_bounds__(256, 2) void pv_kernel(
    const ushort* __restrict__ Qb, const ushort* __restrict__ Kb,
    const ushort* __restrict__ Vt, const ushort* __restrict__ Zinv,
    ushort* __restrict__ Ob) {
    __shared__ ushort sK[2 * 32 * 64];  // [head][k32][d64] swizzled, 8 KB
    __shared__ ushort sV[2 * 64 * 40];  // [head][d64][k32 pad8], 10.25 KB
    __shared__ ushort sZ[64 * 40];      // [q64][k32 pad8], 5.125 KB
    int tid = threadIdx.x, lane = tid & 63, wave = tid >> 6;
    int li = lane & 15, g = lane >> 4;
    int b = blockIdx.y, hp = blockIdx.z;
    int q0 = blockIdx.x * 64;
    int hh = wave & 1, qg = wave >> 1;
    int head = hp * 2 + hh;
    // Q fragments in registers (one-time uncoalesced load)
    short8 qf[2][2];
    #pragma unroll
    for (int qs = 0; qs < 2; qs++)
        #pragma unroll
        for (int dc = 0; dc < 2; dc++)
            qf[qs][dc] = *(const short8*)(
                Qb + (size_t)(b * 2048 + q0 + qg * 32 + qs * 16 + li) * 1024 +
                head * 64 + dc * 32 + g * 8);
    f32x4 oacc[2][4] = {};  // [qs][ds]
    for (int kb = 0; kb < 2048; kb += 32) {
        __syncthreads();
        #pragma unroll
        for (int i = 0; i < 2; i++) {  // K: 2 heads x 32 rows x 8 chunks
            int c = tid + i * 256;
            int h2 = c >> 8, r = (c >> 3) & 31, ch = c & 7;
            int sw = (ch * 16) ^ ((r & 7) << 4);
            *(uint4v*)((char*)sK + h2 * 4096 + r * 128 + sw) =
                *(const uint4v*)(Kb + (size_t)(b * 2048 + kb + r) * 1024 +
                                 (hp * 2 + h2) * 64 + ch * 8);
        }
        #pragma unroll
        for (int i = 0; i < 2; i++) {  // V: 2 heads x 64 rows x 4 chunks
            int c = tid + i * 256;
            int h2 = c >> 8, r = (c >> 2) & 63, ch = c & 3;
            *(uint4v*)(sV + h2 * 2560 + r * 40 + ch * 8) =
                *(const uint4v*)(Vt + (size_t)(b * 1024 + (hp * 2 + h2) * 64 + r) * 2048 +
                                 kb + ch * 8);
        }
        {   // Z: 64 rows x 4 chunks
            int r = tid >> 2, ch = tid & 3;
            *(uint4v*)(sZ + r * 40 + ch * 8) =
                *(const uint4v*)(Zinv + (size_t)(b * 2048 + q0 + r) * 2048 + kb + ch * 8);
        }
        __syncthreads();
        short8 kf[2][2];
        #pragma unroll
        for (int ks = 0; ks < 2; ks++)
            #pragma unroll
            for (int dc = 0; dc < 2; dc++) {
                int row = ks * 16 + li;
                kf[ks][dc] = *(const short8*)(
                    (char*)sK + hh * 4096 + row * 128 +
                    ((dc * 64 + g * 16) ^ ((row & 7) << 4)));
            }
        f32x4 st[2][2];
        #pragma unroll
        for (int qs = 0; qs < 2; qs++)
            #pragma unroll
            for (int ks = 0; ks < 2; ks++) {
                f32x4 t0 = {0.f, 0.f, 0.f, 0.f};
                t0 = MFMA32(kf[ks][0], qf[qs][0], t0);
                t0 = MFMA32(kf[ks][1], qf[qs][1], t0);
                st[qs][ks] = t0;
            }
        short4v pf[2][2];
        #pragma unroll
        for (int qs = 0; qs < 2; qs++)
            #pragma unroll
            for (int ks = 0; ks < 2; ks++) {
                union { ushort u[4]; uint2v v; } rz;
                rz.v = *(const uint2v*)(sZ + (qg * 32 + qs * 16 + li) * 40 + ks * 16 + g * 4);
                short4v p;
                #pragma unroll
                for (int r = 0; r < 4; r++)
                    p[r] = (short)f2bf(__expf(st[qs][ks][r] * 0.03125f) * bf2f(rz.u[r]));
                pf[qs][ks] = p;
            }
        #pragma unroll
        for (int ks = 0; ks < 2; ks++)
            #pragma unroll
            for (int ds = 0; ds < 4; ds++) {
                short4v vf = *(const short4v*)(
                    sV + hh * 2560 + (ds * 16 + li) * 40 + ks * 16 + g * 4);
                oacc[0][ds] = MFMA16(pf[0][ks], vf, oacc[0][ds]);
                oacc[1][ds] = MFMA16(pf[1][ks], vf, oacc[1][ds]);
            }
    }
    ushort* Oo = Ob + (size_t)(b * 2048 + q0 + qg * 32) * 1024 + head * 64;
    #pragma unroll
    for (int qs = 0; qs < 2; qs++)
        #pragma unroll
        for (int ds = 0; ds < 4; ds++)
            #pragma unroll
            for (int r = 0; r < 4; r++)
                Oo[(size_t)(qs * 16 + g * 4 + r) * 1024 + ds * 16 + li] =
                    f2bf(oacc[qs][ds][r]);
}

// ---------------------------------------------------------------------------
extern "C" void kernel_launch(void* const* d_in, const int* in_sizes, int n_in,
                              void* d_out, int out_size, void* d_ws, size_t ws_size,
                              hipStream_t stream) {
    const float* queries = (const float*)d_in[0];
    const float* keys    = (const float*)d_in[1];
    const float* values  = (const float*)d_in[2];
    const float* Wq = (const float*)d_in[3];
    const float* bq = (const float*)d_in[4];
    const float* Wk = (const float*)d_in[5];
    const float* bk = (const float*)d_in[6];
    const float* Wv = (const float*)d_in[7];
    const float* bv = (const float*)d_in[8];
    const float* Wo = (const float*)d_in[9];
    const float* bo = (const float*)d_in[10];
    float* out = (float*)d_out;

    // ws layout (ushort units). Requires ws_size >= 56 MB.
    ushort* Xb  = (ushort*)d_ws;            // [3][4096][1024]   (12M u)
    ushort* Wt  = Xb + 12ull * 1024 * 1024; // [4][1024][1024]   (4M u)
    ushort* Qb  = Wt + 4ull * 1024 * 1024;  // [4096][1024]      (4M u)
    ushort* Kb  = Qb + 4ull * 1024 * 1024;  // [4096][1024]      (4M u)
    ushort* Vtb = Kb + 4ull * 1024 * 1024;  // [2][1024][2048]   (4M u)
    // After projections Xb is dead: Zinv (8M u) and Ob (4M u) alias it.
    ushort* Zinv = Xb;                       // [2][2048][2048] bf16 (8M u)
    ushort* Ob   = Xb + 8ull * 1024 * 1024;  // [4096][1024]        (4M u)

    convert_x_kernel<<<2048, 256, 0, stream>>>(queries, keys, values, Xb);
    transpose_w_kernel<<<dim3(16, 16, 4), 256, 0, stream>>>(Wq, Wk, Wv, Wo, Wt);
    gemm_bt_kernel<0><<<dim3(8, 32), 256, 0, stream>>>(
        Xb, Wt, bq, Qb, nullptr);
    gemm_bt_kernel<0><<<dim3(8, 32), 256, 0, stream>>>(
        Xb + 4ull * 1024 * 1024, Wt + 1ull * 1024 * 1024, bk, Kb, nullptr);
    gemm_bt_kernel<1><<<dim3(8, 32), 256, 0, stream>>>(
        Xb + 8ull * 1024 * 1024, Wt + 2ull * 1024 * 1024, bv, Vtb, nullptr);
    zsum_kernel<<<dim3(64, 16, 2), 256, 0, stream>>>(Qb, Kb, Zinv);
    pv_kernel<<<dim3(32, 2, 8), 256, 0, stream>>>(Qb, Kb, Vtb, Zinv, Ob);
    gemm_bt_kernel<2><<<dim3(8, 32), 256, 0, stream>>>(
        Ob, Wt + 3ull * 1024 * 1024, bo, nullptr, out);
}

// Round 5
// 198.331 us; speedup vs baseline: 3.1592x; 1.2194x over previous
//
#include <hip/hip_runtime.h>

// ---------------------------------------------------------------------------
// MHA with softmax over the HEADS axis (torch legacy F.softmax dim=1).
// B=2, S=2048, D=1024, H=16, dh=64. scale = sqrt(1024) = 32.
//
// Round 5: fix round-4 bug (pv sV head stride: 8192 -> 4096 bytes).
// global_load_lds staging (linear LDS dest + pre-swizzled global source),
// 8-wave pv, fused projection GEMM.
// ws layout (56 MB): [Xb 12M ushorts | Wt 4M | Qb 4M | Kb 4M | Vt 4M]
// Zinv (8M ushorts) aliases Xb[0:8M]; Ob (4M) aliases Xb[8M:12M] (X dead).
// ---------------------------------------------------------------------------

typedef unsigned short ushort;
typedef __attribute__((ext_vector_type(8))) short short8;
typedef __attribute__((ext_vector_type(4))) short short4v;
typedef __attribute__((ext_vector_type(4))) float f32x4;
typedef __attribute__((ext_vector_type(4))) float float4v;
typedef __attribute__((ext_vector_type(4))) unsigned int uint4v;
typedef __attribute__((ext_vector_type(2))) unsigned int uint2v;

#define MFMA32(a, b, c) __builtin_amdgcn_mfma_f32_16x16x32_bf16(a, b, c, 0, 0, 0)
#define MFMA16(a, b, c) __builtin_amdgcn_mfma_f32_16x16x16bf16_1k(a, b, c, 0, 0, 0)

__device__ __forceinline__ ushort f2bf(float f) {  // round-to-nearest-even
    unsigned u = __float_as_uint(f);
    u += 0x7fffu + ((u >> 16) & 1u);
    return (ushort)(u >> 16);
}
__device__ __forceinline__ float bf2f(ushort u) {
    return __uint_as_float(((unsigned)u) << 16);
}

// async global->LDS, 16B per lane. LDS dest must be wave-uniform base +
// lane*16 (linear); swizzled layouts are achieved by permuting the SOURCE.
__device__ __forceinline__ void gload16(const ushort* g, ushort* l) {
    __builtin_amdgcn_global_load_lds(
        (__attribute__((address_space(1))) void*)(unsigned long long)(g),
        (__attribute__((address_space(3))) void*)(l), 16, 0, 0);
}

// ------------------------- 1. convert inputs to bf16 -----------------------
__global__ __launch_bounds__(256) void convert_x_kernel(
    const float* __restrict__ q, const float* __restrict__ k,
    const float* __restrict__ v, ushort* __restrict__ out) {
    const size_t NPER = 4194304ull;  // 4096*1024
    size_t idx = ((size_t)blockIdx.x * 256 + threadIdx.x) * 8;
    const size_t stride = (size_t)gridDim.x * 256 * 8;
    for (; idx < 3 * NPER; idx += stride) {
        const float* src;
        size_t off;
        if (idx < NPER)          { src = q; off = idx; }
        else if (idx < 2 * NPER) { src = k; off = idx - NPER; }
        else                     { src = v; off = idx - 2 * NPER; }
        float4v a = *(const float4v*)(src + off);
        float4v b = *(const float4v*)(src + off + 4);
        union { ushort u[8]; uint4v v4; } pk;
        #pragma unroll
        for (int j = 0; j < 4; j++) { pk.u[j] = f2bf(a[j]); pk.u[4 + j] = f2bf(b[j]); }
        *(uint4v*)(out + idx) = pk.v4;
    }
}

// ------------------- 2. transpose weights: [K][N] -> [N][K] bf16 -----------
__global__ __launch_bounds__(256) void transpose_w_kernel(
    const float* __restrict__ w0, const float* __restrict__ w1,
    const float* __restrict__ w2, const float* __restrict__ w3,
    ushort* __restrict__ Wt) {
    const float* W = blockIdx.z == 0 ? w0 : blockIdx.z == 1 ? w1 : blockIdx.z == 2 ? w2 : w3;
    ushort* out = Wt + (size_t)blockIdx.z * 1024 * 1024;
    __shared__ ushort st[64 * 72];
    int t = threadIdx.x;
    int kb = blockIdx.y * 64, nb = blockIdx.x * 64;
    int c4 = (t & 15) * 4;
    int r0 = t >> 4;
    #pragma unroll
    for (int p = 0; p < 4; p++) {
        int r = r0 + p * 16;
        float4v f = *(const float4v*)(W + (size_t)(kb + r) * 1024 + nb + c4);
        union { ushort u[4]; uint2v v2; } pk;
        #pragma unroll
        for (int j = 0; j < 4; j++) pk.u[j] = f2bf(f[j]);
        *(uint2v*)(st + r * 72 + c4) = pk.v2;
    }
    __syncthreads();
    int n = t >> 2;
    int kc = (t & 3) * 16;
    union { ushort u[16]; uint4v v4[2]; } tw;
    #pragma unroll
    for (int j = 0; j < 16; j++) tw.u[j] = st[(kc + j) * 72 + n];
    uint4v* dst = (uint4v*)(out + (size_t)(nb + n) * 1024 + kb + kc);
    dst[0] = tw.v4[0];
    dst[1] = tw.v4[1];
}

// ------------------- 3./6. GEMM core: C[4096][1024] = A * Bt^T -------------
// gload_lds staging: linear LDS dest, source chunk pre-swizzled by row so
// the read side keeps the XOR form (bank-conflict-free ds_read_b128).
// mode 0: bf16 row-major out.  mode 1: bf16 per-batch transposed (Vt).
// mode 2: f32 out + bias.
__device__ __forceinline__ void gemm_core(
    const ushort* __restrict__ A, const ushort* __restrict__ Bt,
    const float* __restrict__ bias, ushort* __restrict__ Cb,
    float* __restrict__ Cf, int mode, ushort* sA, ushort* sB) {
    int tid = threadIdx.x, lane = tid & 63, wave = tid >> 6;
    int li = lane & 15, g = lane >> 4;
    int mt = blockIdx.y * 128, nt = blockIdx.x * 128;
    int wm = (wave >> 1) * 64, wn = (wave & 1) * 64;
    f32x4 acc[4][4] = {};
    for (int k0 = 0; k0 < 1024; k0 += 64) {
        __syncthreads();
        #pragma unroll
        for (int i = 0; i < 4; i++) {
            int c = tid + i * 256;              // 16B-chunk id, 0..1023
            int row = c >> 3, chd = c & 7;
            int cg = chd ^ (row & 7);           // pre-swizzled source chunk
            gload16(A + (size_t)(mt + row) * 1024 + k0 + cg * 8, sA + c * 8);
            gload16(Bt + (size_t)(nt + row) * 1024 + k0 + cg * 8, sB + c * 8);
        }
        __syncthreads();
        #pragma unroll
        for (int kk = 0; kk < 2; kk++) {
            short8 af[4], bfr[4];
            #pragma unroll
            for (int i = 0; i < 4; i++) {
                int ra = wm + i * 16 + li;
                int cb = kk * 64 + g * 16;
                af[i] = *(const short8*)((char*)sA + ra * 128 + (cb ^ ((ra & 7) << 4)));
                int rb = wn + i * 16 + li;
                bfr[i] = *(const short8*)((char*)sB + rb * 128 + (cb ^ ((rb & 7) << 4)));
            }
            #pragma unroll
            for (int mi = 0; mi < 4; mi++)
                #pragma unroll
                for (int ni = 0; ni < 4; ni++)
                    acc[mi][ni] = MFMA32(af[mi], bfr[ni], acc[mi][ni]);
        }
    }
    #pragma unroll
    for (int mi = 0; mi < 4; mi++) {
        #pragma unroll
        for (int ni = 0; ni < 4; ni++) {
            int n = nt + wn + ni * 16 + li;
            int m0 = mt + wm + mi * 16 + g * 4;
            float bv = bias[n];
            if (mode == 0) {
                #pragma unroll
                for (int r = 0; r < 4; r++)
                    Cb[(size_t)(m0 + r) * 1024 + n] = f2bf(acc[mi][ni][r] + bv);
            } else if (mode == 1) {
                int batch = m0 >> 11, mm = m0 & 2047;
                union { ushort u[4]; uint2v v2; } pk;
                #pragma unroll
                for (int r = 0; r < 4; r++) pk.u[r] = f2bf(acc[mi][ni][r] + bv);
                *(uint2v*)(Cb + (size_t)batch * 1024 * 2048 + (size_t)n * 2048 + mm) = pk.v2;
            } else {
                #pragma unroll
                for (int r = 0; r < 4; r++)
                    Cf[(size_t)(m0 + r) * 1024 + n] = acc[mi][ni][r] + bv;
            }
        }
    }
}

// fused Q/K/V projections: blockIdx.z selects the GEMM (3x blocks in flight)
__global__ __launch_bounds__(256, 2) void proj_kernel(
    const ushort* __restrict__ Xb, const ushort* __restrict__ Wt,
    const float* __restrict__ bq, const float* __restrict__ bk,
    const float* __restrict__ bv, ushort* __restrict__ Qb,
    ushort* __restrict__ Kb, ushort* __restrict__ Vtb) {
    __shared__ ushort sA[128 * 64];
    __shared__ ushort sB[128 * 64];
    int z = blockIdx.z;
    const float* bias = z == 0 ? bq : (z == 1 ? bk : bv);
    ushort* out = z == 0 ? Qb : (z == 1 ? Kb : Vtb);
    gemm_core(Xb + (size_t)z * 4194304ull, Wt + (size_t)z * 1048576ull,
              bias, out, nullptr, z == 2 ? 1 : 0, sA, sB);
}

__global__ __launch_bounds__(256, 2) void outproj_kernel(
    const ushort* __restrict__ Ob, const ushort* __restrict__ Wt3,
    const float* __restrict__ bo, float* __restrict__ out) {
    __shared__ ushort sA[128 * 64];
    __shared__ ushort sB[128 * 64];
    gemm_core(Ob, Wt3, bo, nullptr, out, 2, sA, sB);
}

// ------------------- 4. zsum: rz = 1/sum_h exp(S/32) -----------------------
// grid (64 qt, 16 kg, 2 b), 256 thr = 4 waves. Block = 32q x 128k; wave owns
// 32k. Per head: gload_lds-stage Q[32][64] + K[128][64] (source-swizzled).
__global__ __launch_bounds__(256, 4) void zsum_kernel(
    const ushort* __restrict__ Qb, const ushort* __restrict__ Kb,
    ushort* __restrict__ Zinv) {
    __shared__ ushort sQ[32 * 64];   // 4 KB
    __shared__ ushort sK[128 * 64];  // 16 KB
    int tid = threadIdx.x, lane = tid & 63, wave = tid >> 6;
    int li = lane & 15, g = lane >> 4;
    int b = blockIdx.z;
    int q0 = blockIdx.x * 32;
    int k0 = blockIdx.y * 128;
    const ushort* Qp = Qb + (size_t)(b * 2048 + q0) * 1024;
    const ushort* Kp = Kb + (size_t)(b * 2048 + k0) * 1024;
    int qr = tid >> 3, qc = tid & 7;
    int qcg = qc ^ (qr & 7);
    f32x4 zacc[2][2] = {};
    for (int h = 0; h < 16; h++) {
        int co = h * 64;
        __syncthreads();
        gload16(Qp + (size_t)qr * 1024 + co + qcg * 8, sQ + tid * 8);
        #pragma unroll
        for (int i = 0; i < 4; i++) {
            int c = tid + i * 256;
            int r = c >> 3, chd = c & 7;
            int cg = chd ^ (r & 7);
            gload16(Kp + (size_t)r * 1024 + co + cg * 8, sK + c * 8);
        }
        __syncthreads();
        short8 qf[2][2], kf[2][2];
        #pragma unroll
        for (int qs = 0; qs < 2; qs++)
            #pragma unroll
            for (int dc = 0; dc < 2; dc++) {
                int row = qs * 16 + li;
                qf[qs][dc] = *(const short8*)(
                    (char*)sQ + row * 128 + ((dc * 64 + g * 16) ^ ((row & 7) << 4)));
            }
        #pragma unroll
        for (int ks = 0; ks < 2; ks++)
            #pragma unroll
            for (int dc = 0; dc < 2; dc++) {
                int row = wave * 32 + ks * 16 + li;
                kf[ks][dc] = *(const short8*)(
                    (char*)sK + row * 128 + ((dc * 64 + g * 16) ^ ((row & 7) << 4)));
            }
        #pragma unroll
        for (int qs = 0; qs < 2; qs++)
            #pragma unroll
            for (int ks = 0; ks < 2; ks++) {
                f32x4 st = {0.f, 0.f, 0.f, 0.f};
                st = MFMA32(kf[ks][0], qf[qs][0], st);
                st = MFMA32(kf[ks][1], qf[qs][1], st);
                #pragma unroll
                for (int r = 0; r < 4; r++)
                    zacc[qs][ks][r] += __expf(st[r] * 0.03125f);
            }
    }
    #pragma unroll
    for (int qs = 0; qs < 2; qs++)
        #pragma unroll
        for (int ks = 0; ks < 2; ks++) {
            union { ushort u[4]; uint2v v; } pk;
            #pragma unroll
            for (int r = 0; r < 4; r++)
                pk.u[r] = f2bf(__builtin_amdgcn_rcpf(zacc[qs][ks][r]));
            *(uint2v*)(Zinv + (size_t)(b * 2048 + q0 + qs * 16 + li) * 2048 +
                       k0 + wave * 32 + ks * 16 + g * 4) = pk.v;
        }
}

// ------------------- 5. pv: recompute S, w = exp*rz, O += w@V --------------
// grid (32 qt, 2 b, 8 hp), 512 thr = 8 waves. Block = 64q x 2 heads; wave =
// 16q x 1 head (verified round-2 fragment flow). Per 32-k step gload_lds-
// stage K[2][32][64] (swz8), V[2][64][32] (swz4), Z[64][32] (swz4).
__global__ __launch_bounds__(512, 2) void pv_kernel(
    const ushort* __restrict__ Qb, const ushort* __restrict__ Kb,
    const ushort* __restrict__ Vt, const ushort* __restrict__ Zinv,
    ushort* __restrict__ Ob) {
    __shared__ ushort sK[2 * 32 * 64];  // 8 KB, head stride 4096 B
    __shared__ ushort sV[2 * 64 * 32];  // 8 KB, head stride 4096 B
    __shared__ ushort sZ[64 * 32];      // 4 KB
    int tid = threadIdx.x, lane = tid & 63, wave = tid >> 6;
    int li = lane & 15, g = lane >> 4;
    int b = blockIdx.y, hp = blockIdx.z;
    int q0 = blockIdx.x * 64;
    int hh = wave & 1, qg = wave >> 1;  // qg in 0..3
    int head = hp * 2 + hh;
    // Q fragments in registers (one-time gather)
    short8 qf[2];
    #pragma unroll
    for (int dc = 0; dc < 2; dc++)
        qf[dc] = *(const short8*)(
            Qb + (size_t)(b * 2048 + q0 + qg * 16 + li) * 1024 +
            head * 64 + dc * 32 + g * 8);
    f32x4 oacc[4] = {};
    // staging index precompute (source-swizzled, linear LDS dest)
    int kc_h2 = tid >> 8, kc_r = (tid >> 3) & 31, kc_c = tid & 7;
    int kc_cg = kc_c ^ (kc_r & 7);
    int vc_h2 = tid >> 8, vc_r = (tid >> 2) & 63, vc_c = tid & 3;
    int vc_cg = vc_c ^ (vc_r & 3);
    int zc_r = (tid & 255) >> 2, zc_c = tid & 3;
    int zc_cg = zc_c ^ (zc_r & 3);
    const ushort* Ksrc = Kb + (size_t)(b * 2048 + kc_r) * 1024 +
                         (hp * 2 + kc_h2) * 64 + kc_cg * 8;
    const ushort* Vsrc = Vt + (size_t)(b * 1024 + (hp * 2 + vc_h2) * 64 + vc_r) * 2048 +
                         vc_cg * 8;
    const ushort* Zsrc = Zinv + (size_t)(b * 2048 + q0 + zc_r) * 2048 + zc_cg * 8;
    ushort* Kdst = sK + tid * 8;
    ushort* Vdst = sV + tid * 8;
    ushort* Zdst = sZ + (tid & 255) * 8;
    int rw = qg * 16 + li;
    for (int kb = 0; kb < 2048; kb += 32) {
        __syncthreads();
        gload16(Ksrc + (size_t)kb * 1024, Kdst);
        gload16(Vsrc + kb, Vdst);
        if (tid < 256) gload16(Zsrc + kb, Zdst);
        __syncthreads();
        short8 kf[2][2];
        #pragma unroll
        for (int ks = 0; ks < 2; ks++)
            #pragma unroll
            for (int dc = 0; dc < 2; dc++) {
                int rk = ks * 16 + li;
                kf[ks][dc] = *(const short8*)(
                    (char*)sK + hh * 4096 + rk * 128 +
                    ((dc * 64 + g * 16) ^ ((rk & 7) << 4)));
            }
        f32x4 st[2];
        #pragma unroll
        for (int ks = 0; ks < 2; ks++) {
            f32x4 t0 = {0.f, 0.f, 0.f, 0.f};
            t0 = MFMA32(kf[ks][0], qf[0], t0);
            t0 = MFMA32(kf[ks][1], qf[1], t0);
            st[ks] = t0;
        }
        short4v pf[2];
        #pragma unroll
        for (int ks = 0; ks < 2; ks++) {
            int l = ks * 2 + (g >> 1);
            union { ushort u[4]; uint2v v; } rz;
            rz.v = *(const uint2v*)(
                (char*)sZ + rw * 64 + ((l ^ (rw & 3)) << 4) + (g & 1) * 8);
            short4v p;
            #pragma unroll
            for (int r = 0; r < 4; r++)
                p[r] = (short)f2bf(__expf(st[ks][r] * 0.03125f) * bf2f(rz.u[r]));
            pf[ks] = p;
        }
        #pragma unroll
        for (int ks = 0; ks < 2; ks++) {
            int l = ks * 2 + (g >> 1);
            #pragma unroll
            for (int ds = 0; ds < 4; ds++) {
                int rv = ds * 16 + li;
                short4v vf = *(const short4v*)(
                    (char*)sV + hh * 4096 + rv * 64 + ((l ^ (rv & 3)) << 4) + (g & 1) * 8);
                oacc[ds] = MFMA16(pf[ks], vf, oacc[ds]);
            }
        }
    }
    ushort* Oo = Ob + (size_t)(b * 2048 + q0 + qg * 16) * 1024 + head * 64;
    #pragma unroll
    for (int ds = 0; ds < 4; ds++)
        #pragma unroll
        for (int r = 0; r < 4; r++)
            Oo[(size_t)(g * 4 + r) * 1024 + ds * 16 + li] = f2bf(oacc[ds][r]);
}

// ---------------------------------------------------------------------------
extern "C" void kernel_launch(void* const* d_in, const int* in_sizes, int n_in,
                              void* d_out, int out_size, void* d_ws, size_t ws_size,
                              hipStream_t stream) {
    const float* queries = (const float*)d_in[0];
    const float* keys    = (const float*)d_in[1];
    const float* values  = (const float*)d_in[2];
    const float* Wq = (const float*)d_in[3];
    const float* bq = (const float*)d_in[4];
    const float* Wk = (const float*)d_in[5];
    const float* bk = (const float*)d_in[6];
    const float* Wv = (const float*)d_in[7];
    const float* bv = (const float*)d_in[8];
    const float* Wo = (const float*)d_in[9];
    const float* bo = (const float*)d_in[10];
    float* out = (float*)d_out;

    // ws layout (ushort units). Requires ws_size >= 56 MB.
    ushort* Xb  = (ushort*)d_ws;            // [3][4096][1024]   (12M u)
    ushort* Wt  = Xb + 12ull * 1024 * 1024; // [4][1024][1024]   (4M u)
    ushort* Qb  = Wt + 4ull * 1024 * 1024;  // [4096][1024]      (4M u)
    ushort* Kb  = Qb + 4ull * 1024 * 1024;  // [4096][1024]      (4M u)
    ushort* Vtb = Kb + 4ull * 1024 * 1024;  // [2][1024][2048]   (4M u)
    // After projections Xb is dead: Zinv (8M u) and Ob (4M u) alias it.
    ushort* Zinv = Xb;                       // [2][2048][2048] bf16 (8M u)
    ushort* Ob   = Xb + 8ull * 1024 * 1024;  // [4096][1024]        (4M u)

    convert_x_kernel<<<2048, 256, 0, stream>>>(queries, keys, values, Xb);
    transpose_w_kernel<<<dim3(16, 16, 4), 256, 0, stream>>>(Wq, Wk, Wv, Wo, Wt);
    proj_kernel<<<dim3(8, 32, 3), 256, 0, stream>>>(Xb, Wt, bq, bk, bv, Qb, Kb, Vtb);
    zsum_kernel<<<dim3(64, 16, 2), 256, 0, stream>>>(Qb, Kb, Zinv);
    pv_kernel<<<dim3(32, 2, 8), 512, 0, stream>>>(Qb, Kb, Vtb, Zinv, Ob);
    outproj_kernel<<<dim3(8, 32), 256, 0, stream>>>(Ob, Wt + 3ull * 1024 * 1024, bo, out);
}

// Round 6
// 194.891 us; speedup vs baseline: 3.2150x; 1.0177x over previous
//
#include <hip/hip_runtime.h>

// ---------------------------------------------------------------------------
// MHA with softmax over the HEADS axis (torch legacy F.softmax dim=1).
// B=2, S=2048, D=1024, H=16, dh=64. scale = sqrt(1024) = 32.
//
// Round 6: pv rewritten (32q x 4heads blocks, wave = 32q x 1 head, dbuf LDS,
// uniform-4-way 8B swizzle, XCD-chunked (qt,b) with hp-fast order); zsum
// widened to 64q blocks with XCD-chunked K-slices. Two-pass Z kept.
// ws layout (56 MB): [Xb 12M ushorts | Wt 4M | Qb 4M | Kb 4M | Vt 4M]
// Zinv (8M u) aliases Xb[0:8M]; Ob (4M u) aliases Xb[8M:12M] (X dead).
// ---------------------------------------------------------------------------

typedef unsigned short ushort;
typedef __attribute__((ext_vector_type(8))) short short8;
typedef __attribute__((ext_vector_type(4))) short short4v;
typedef __attribute__((ext_vector_type(4))) float f32x4;
typedef __attribute__((ext_vector_type(4))) float float4v;
typedef __attribute__((ext_vector_type(4))) unsigned int uint4v;
typedef __attribute__((ext_vector_type(2))) unsigned int uint2v;

#define MFMA32(a, b, c) __builtin_amdgcn_mfma_f32_16x16x32_bf16(a, b, c, 0, 0, 0)
#define MFMA16(a, b, c) __builtin_amdgcn_mfma_f32_16x16x16bf16_1k(a, b, c, 0, 0, 0)

__device__ __forceinline__ ushort f2bf(float f) {  // round-to-nearest-even
    unsigned u = __float_as_uint(f);
    u += 0x7fffu + ((u >> 16) & 1u);
    return (ushort)(u >> 16);
}
__device__ __forceinline__ float bf2f(ushort u) {
    return __uint_as_float(((unsigned)u) << 16);
}

// async global->LDS, 16B per lane. LDS dest must be wave-uniform base +
// lane*16 (linear); swizzled layouts are achieved by permuting the SOURCE.
__device__ __forceinline__ void gload16(const ushort* g, ushort* l) {
    __builtin_amdgcn_global_load_lds(
        (__attribute__((address_space(1))) void*)(unsigned long long)(g),
        (__attribute__((address_space(3))) void*)(l), 16, 0, 0);
}

// ------------------------- 1. convert inputs to bf16 -----------------------
__global__ __launch_bounds__(256) void convert_x_kernel(
    const float* __restrict__ q, const float* __restrict__ k,
    const float* __restrict__ v, ushort* __restrict__ out) {
    const size_t NPER = 4194304ull;  // 4096*1024
    size_t idx = ((size_t)blockIdx.x * 256 + threadIdx.x) * 8;
    const size_t stride = (size_t)gridDim.x * 256 * 8;
    for (; idx < 3 * NPER; idx += stride) {
        const float* src;
        size_t off;
        if (idx < NPER)          { src = q; off = idx; }
        else if (idx < 2 * NPER) { src = k; off = idx - NPER; }
        else                     { src = v; off = idx - 2 * NPER; }
        float4v a = *(const float4v*)(src + off);
        float4v b = *(const float4v*)(src + off + 4);
        union { ushort u[8]; uint4v v4; } pk;
        #pragma unroll
        for (int j = 0; j < 4; j++) { pk.u[j] = f2bf(a[j]); pk.u[4 + j] = f2bf(b[j]); }
        *(uint4v*)(out + idx) = pk.v4;
    }
}

// ------------------- 2. transpose weights: [K][N] -> [N][K] bf16 -----------
__global__ __launch_bounds__(256) void transpose_w_kernel(
    const float* __restrict__ w0, const float* __restrict__ w1,
    const float* __restrict__ w2, const float* __restrict__ w3,
    ushort* __restrict__ Wt) {
    const float* W = blockIdx.z == 0 ? w0 : blockIdx.z == 1 ? w1 : blockIdx.z == 2 ? w2 : w3;
    ushort* out = Wt + (size_t)blockIdx.z * 1024 * 1024;
    __shared__ ushort st[64 * 72];
    int t = threadIdx.x;
    int kb = blockIdx.y * 64, nb = blockIdx.x * 64;
    int c4 = (t & 15) * 4;
    int r0 = t >> 4;
    #pragma unroll
    for (int p = 0; p < 4; p++) {
        int r = r0 + p * 16;
        float4v f = *(const float4v*)(W + (size_t)(kb + r) * 1024 + nb + c4);
        union { ushort u[4]; uint2v v2; } pk;
        #pragma unroll
        for (int j = 0; j < 4; j++) pk.u[j] = f2bf(f[j]);
        *(uint2v*)(st + r * 72 + c4) = pk.v2;
    }
    __syncthreads();
    int n = t >> 2;
    int kc = (t & 3) * 16;
    union { ushort u[16]; uint4v v4[2]; } tw;
    #pragma unroll
    for (int j = 0; j < 16; j++) tw.u[j] = st[(kc + j) * 72 + n];
    uint4v* dst = (uint4v*)(out + (size_t)(nb + n) * 1024 + kb + kc);
    dst[0] = tw.v4[0];
    dst[1] = tw.v4[1];
}

// ------------------- 3./6. GEMM core: C[4096][1024] = A * Bt^T -------------
__device__ __forceinline__ void gemm_core(
    const ushort* __restrict__ A, const ushort* __restrict__ Bt,
    const float* __restrict__ bias, ushort* __restrict__ Cb,
    float* __restrict__ Cf, int mode, ushort* sA, ushort* sB) {
    int tid = threadIdx.x, lane = tid & 63, wave = tid >> 6;
    int li = lane & 15, g = lane >> 4;
    int mt = blockIdx.y * 128, nt = blockIdx.x * 128;
    int wm = (wave >> 1) * 64, wn = (wave & 1) * 64;
    f32x4 acc[4][4] = {};
    for (int k0 = 0; k0 < 1024; k0 += 64) {
        __syncthreads();
        #pragma unroll
        for (int i = 0; i < 4; i++) {
            int c = tid + i * 256;              // 16B-chunk id, 0..1023
            int row = c >> 3, chd = c & 7;
            int cg = chd ^ (row & 7);           // pre-swizzled source chunk
            gload16(A + (size_t)(mt + row) * 1024 + k0 + cg * 8, sA + c * 8);
            gload16(Bt + (size_t)(nt + row) * 1024 + k0 + cg * 8, sB + c * 8);
        }
        __syncthreads();
        #pragma unroll
        for (int kk = 0; kk < 2; kk++) {
            short8 af[4], bfr[4];
            #pragma unroll
            for (int i = 0; i < 4; i++) {
                int ra = wm + i * 16 + li;
                int cb = kk * 64 + g * 16;
                af[i] = *(const short8*)((char*)sA + ra * 128 + (cb ^ ((ra & 7) << 4)));
                int rb = wn + i * 16 + li;
                bfr[i] = *(const short8*)((char*)sB + rb * 128 + (cb ^ ((rb & 7) << 4)));
            }
            #pragma unroll
            for (int mi = 0; mi < 4; mi++)
                #pragma unroll
                for (int ni = 0; ni < 4; ni++)
                    acc[mi][ni] = MFMA32(af[mi], bfr[ni], acc[mi][ni]);
        }
    }
    #pragma unroll
    for (int mi = 0; mi < 4; mi++) {
        #pragma unroll
        for (int ni = 0; ni < 4; ni++) {
            int n = nt + wn + ni * 16 + li;
            int m0 = mt + wm + mi * 16 + g * 4;
            float bv = bias[n];
            if (mode == 0) {
                #pragma unroll
                for (int r = 0; r < 4; r++)
                    Cb[(size_t)(m0 + r) * 1024 + n] = f2bf(acc[mi][ni][r] + bv);
            } else if (mode == 1) {
                int batch = m0 >> 11, mm = m0 & 2047;
                union { ushort u[4]; uint2v v2; } pk;
                #pragma unroll
                for (int r = 0; r < 4; r++) pk.u[r] = f2bf(acc[mi][ni][r] + bv);
                *(uint2v*)(Cb + (size_t)batch * 1024 * 2048 + (size_t)n * 2048 + mm) = pk.v2;
            } else {
                #pragma unroll
                for (int r = 0; r < 4; r++)
                    Cf[(size_t)(m0 + r) * 1024 + n] = acc[mi][ni][r] + bv;
            }
        }
    }
}

__global__ __launch_bounds__(256, 2) void proj_kernel(
    const ushort* __restrict__ Xb, const ushort* __restrict__ Wt,
    const float* __restrict__ bq, const float* __restrict__ bk,
    const float* __restrict__ bv, ushort* __restrict__ Qb,
    ushort* __restrict__ Kb, ushort* __restrict__ Vtb) {
    __shared__ ushort sA[128 * 64];
    __shared__ ushort sB[128 * 64];
    int z = blockIdx.z;
    const float* bias = z == 0 ? bq : (z == 1 ? bk : bv);
    ushort* out = z == 0 ? Qb : (z == 1 ? Kb : Vtb);
    gemm_core(Xb + (size_t)z * 4194304ull, Wt + (size_t)z * 1048576ull,
              bias, out, nullptr, z == 2 ? 1 : 0, sA, sB);
}

__global__ __launch_bounds__(256, 2) void outproj_kernel(
    const ushort* __restrict__ Ob, const ushort* __restrict__ Wt3,
    const float* __restrict__ bo, float* __restrict__ out) {
    __shared__ ushort sA[128 * 64];
    __shared__ ushort sB[128 * 64];
    gemm_core(Ob, Wt3, bo, nullptr, out, 2, sA, sB);
}

// ------------------- 4. zsum: rz = 1/sum_h exp(S/32) -----------------------
// 1024 blocks (flat, XCD-chunked), 256 thr = 4 waves. Block = 64q x 128k;
// wave owns 32k, 4 q-subtiles. Per head: gload_lds-stage Q[64][64]+K[128][64].
__global__ __launch_bounds__(256, 2) void zsum_kernel(
    const ushort* __restrict__ Qb, const ushort* __restrict__ Kb,
    ushort* __restrict__ Zinv) {
    __shared__ ushort sQ[64 * 64];   // 8 KB
    __shared__ ushort sK[128 * 64];  // 16 KB
    int tid = threadIdx.x, lane = tid & 63, wid = tid >> 6;
    int li = lane & 15, g = lane >> 4;
    // XCD swizzle: xcd = bid&7 owns 1 batch x 4 kg; qt runs fastest.
    int bid = blockIdx.x;
    int swz = (bid & 7) * 128 + (bid >> 3);
    int qt = swz & 31, C = swz >> 5;       // C in 0..31
    int b = C >> 4, kg = C & 15;
    int q0 = qt * 64, k0 = kg * 128;
    const ushort* Qp = Qb + (size_t)(b * 2048 + q0) * 1024;
    const ushort* Kp = Kb + (size_t)(b * 2048 + k0) * 1024;
    f32x4 zacc[4][2] = {};
    for (int h = 0; h < 16; h++) {
        int co = h * 64;
        __syncthreads();
        #pragma unroll
        for (int i = 0; i < 2; i++) {   // Q: 512 chunks
            int c = tid + i * 256;
            int r = c >> 3, m = c & 7;
            gload16(Qp + (size_t)r * 1024 + co + (m ^ (r & 7)) * 8, sQ + c * 8);
        }
        #pragma unroll
        for (int i = 0; i < 4; i++) {   // K: 1024 chunks
            int c = tid + i * 256;
            int r = c >> 3, m = c & 7;
            gload16(Kp + (size_t)r * 1024 + co + (m ^ (r & 7)) * 8, sK + c * 8);
        }
        __syncthreads();
        short8 qf[4][2], kf[2][2];
        #pragma unroll
        for (int qs = 0; qs < 4; qs++)
            #pragma unroll
            for (int dc = 0; dc < 2; dc++) {
                int row = qs * 16 + li;
                qf[qs][dc] = *(const short8*)(
                    (char*)sQ + row * 128 + ((dc * 64 + g * 16) ^ ((row & 7) << 4)));
            }
        #pragma unroll
        for (int ks = 0; ks < 2; ks++)
            #pragma unroll
            for (int dc = 0; dc < 2; dc++) {
                int row = wid * 32 + ks * 16 + li;
                kf[ks][dc] = *(const short8*)(
                    (char*)sK + row * 128 + ((dc * 64 + g * 16) ^ ((row & 7) << 4)));
            }
        #pragma unroll
        for (int qs = 0; qs < 4; qs++)
            #pragma unroll
            for (int ks = 0; ks < 2; ks++) {
                f32x4 st = {0.f, 0.f, 0.f, 0.f};
                st = MFMA32(kf[ks][0], qf[qs][0], st);
                st = MFMA32(kf[ks][1], qf[qs][1], st);
                #pragma unroll
                for (int r = 0; r < 4; r++)
                    zacc[qs][ks][r] += __expf(st[r] * 0.03125f);
            }
    }
    #pragma unroll
    for (int qs = 0; qs < 4; qs++)
        #pragma unroll
        for (int ks = 0; ks < 2; ks++) {
            union { ushort u[4]; uint2v v; } pk;
            #pragma unroll
            for (int r = 0; r < 4; r++)
                pk.u[r] = f2bf(__builtin_amdgcn_rcpf(zacc[qs][ks][r]));
            *(uint2v*)(Zinv + (size_t)(b * 2048 + q0 + qs * 16 + li) * 2048 +
                       k0 + wid * 32 + ks * 16 + g * 4) = pk.v;
        }
}

// ------------------- 5. pv: recompute S, w = exp*rz, O += w@V --------------
// 512 blocks (flat, XCD-chunked by (qt,b), hp fastest), 256 thr = 4 waves.
// Block = 32q x 4 heads; wave = 32q x 1 head (kf/vf each read once/block).
// Double-buffered gload_lds staging; K swz at 16B, V/Z swz at 16B-pair so
// b64 reads are uniform 4-way (= floor, conflict-free).
__global__ __launch_bounds__(256, 2) void pv_kernel(
    const ushort* __restrict__ Qb, const ushort* __restrict__ Kb,
    const ushort* __restrict__ Vt, const ushort* __restrict__ Zinv,
    ushort* __restrict__ Ob) {
    __shared__ ushort sK[2][4 * 32 * 64];  // 16 KB per buf
    __shared__ ushort sV[2][4 * 64 * 32];  // 16 KB per buf
    __shared__ ushort sZ[2][32 * 32];      // 2 KB per buf
    int tid = threadIdx.x, lane = tid & 63, hh = tid >> 6;
    int li = lane & 15, g = lane >> 4;
    int bid = blockIdx.x;
    int swz = (bid & 7) * 64 + (bid >> 3);
    int hp = swz & 3, p = swz >> 2;        // p in 0..127
    int b = p >> 6, qt = p & 63;
    int q0 = qt * 32;
    int head = hp * 4 + hh;
    // Q fragments in registers (one-time gather)
    short8 qf[2][2];
    #pragma unroll
    for (int qs = 0; qs < 2; qs++)
        #pragma unroll
        for (int dc = 0; dc < 2; dc++)
            qf[qs][dc] = *(const short8*)(
                Qb + (size_t)(b * 2048 + q0 + qs * 16 + li) * 1024 +
                head * 64 + dc * 32 + g * 8);
    f32x4 oacc[2][4] = {};
    // staging decode (source-swizzled, linear LDS dest)
    int kc_h = 0, kc_r = (tid >> 3) & 31, kc_m = tid & 7;       // + i*256: h=i
    int vc_r = (tid >> 2) & 63, vc_m = tid & 3;
    int zc_r = tid >> 2, zc_m = tid & 3;                        // tid<128
    const ushort* Kst = Kb + (size_t)(b * 2048 + kc_r) * 1024 + hp * 256 +
                        (kc_m ^ (kc_r & 7)) * 8;                // + h*64 later
    const ushort* Vst = Vt + (size_t)(b * 1024 + hp * 256 + vc_r) * 2048 +
                        (vc_m ^ ((vc_r >> 1) & 3)) * 8;         // + h*64*2048
    const ushort* Zst = Zinv + (size_t)(b * 2048 + q0 + zc_r) * 2048 +
                        (zc_m ^ ((zc_r >> 1) & 3)) * 8;
    #define PV_STAGE(BUF, KB)                                                  \
        {                                                                      \
            _Pragma("unroll") for (int i = 0; i < 4; i++)                      \
                gload16(Kst + (size_t)(KB) * 1024 + i * 64,                    \
                        sK[BUF] + (tid + i * 256) * 8);                        \
            _Pragma("unroll") for (int i = 0; i < 4; i++)                      \
                gload16(Vst + (size_t)i * 64 * 2048 + (KB),                    \
                        sV[BUF] + (tid + i * 256) * 8);                        \
            if (tid < 128) gload16(Zst + (KB), sZ[BUF] + tid * 8);             \
        }
    PV_STAGE(0, 0)
    __syncthreads();
    for (int it = 0; it < 64; ++it) {
        int cur = it & 1;
        int kb = it * 32;
        if (it + 1 < 64) PV_STAGE(cur ^ 1, kb + 32)
        // ---- QK^T from sK[cur] ----
        short8 kf[2][2];
        #pragma unroll
        for (int ks = 0; ks < 2; ks++)
            #pragma unroll
            for (int dc = 0; dc < 2; dc++) {
                int rk = ks * 16 + li;
                kf[ks][dc] = *(const short8*)(
                    (char*)sK[cur] + hh * 4096 + rk * 128 +
                    ((dc * 64 + g * 16) ^ ((rk & 7) << 4)));
            }
        short4v pf[2][2];  // [qs][ks]
        #pragma unroll
        for (int qs = 0; qs < 2; qs++)
            #pragma unroll
            for (int ks = 0; ks < 2; ks++) {
                f32x4 st = {0.f, 0.f, 0.f, 0.f};
                st = MFMA32(kf[ks][0], qf[qs][0], st);
                st = MFMA32(kf[ks][1], qf[qs][1], st);
                int sl = ks * 4 + g;
                int rq = qs * 16 + li;
                union { ushort u[4]; uint2v v; } rz;
                rz.v = *(const uint2v*)(
                    (char*)sZ[cur] + rq * 64 +
                    (((sl >> 1) ^ ((li >> 1) & 3)) * 2 + (sl & 1)) * 8);
                short4v pp;
                #pragma unroll
                for (int r = 0; r < 4; r++)
                    pp[r] = (short)f2bf(__expf(st[r] * 0.03125f) * bf2f(rz.u[r]));
                pf[qs][ks] = pp;
            }
        // ---- PV from sV[cur] ----
        #pragma unroll
        for (int ks = 0; ks < 2; ks++) {
            int sl = ks * 4 + g;
            #pragma unroll
            for (int ds = 0; ds < 4; ds++) {
                int rv = ds * 16 + li;
                short4v vf = *(const short4v*)(
                    (char*)sV[cur] + hh * 4096 + rv * 64 +
                    (((sl >> 1) ^ ((li >> 1) & 3)) * 2 + (sl & 1)) * 8);
                oacc[0][ds] = MFMA16(pf[0][ks], vf, oacc[0][ds]);
                oacc[1][ds] = MFMA16(pf[1][ks], vf, oacc[1][ds]);
            }
        }
        __syncthreads();
    }
    #undef PV_STAGE
    ushort* Oo = Ob + (size_t)(b * 2048 + q0) * 1024 + head * 64;
    #pragma unroll
    for (int qs = 0; qs < 2; qs++)
        #pragma unroll
        for (int ds = 0; ds < 4; ds++)
            #pragma unroll
            for (int r = 0; r < 4; r++)
                Oo[(size_t)(qs * 16 + g * 4 + r) * 1024 + ds * 16 + li] =
                    f2bf(oacc[qs][ds][r]);
}

// ---------------------------------------------------------------------------
extern "C" void kernel_launch(void* const* d_in, const int* in_sizes, int n_in,
                              void* d_out, int out_size, void* d_ws, size_t ws_size,
                              hipStream_t stream) {
    const float* queries = (const float*)d_in[0];
    const float* keys    = (const float*)d_in[1];
    const float* values  = (const float*)d_in[2];
    const float* Wq = (const float*)d_in[3];
    const float* bq = (const float*)d_in[4];
    const float* Wk = (const float*)d_in[5];
    const float* bk = (const float*)d_in[6];
    const float* Wv = (const float*)d_in[7];
    const float* bv = (const float*)d_in[8];
    const float* Wo = (const float*)d_in[9];
    const float* bo = (const float*)d_in[10];
    float* out = (float*)d_out;

    // ws layout (ushort units). Requires ws_size >= 56 MB.
    ushort* Xb  = (ushort*)d_ws;            // [3][4096][1024]   (12M u)
    ushort* Wt  = Xb + 12ull * 1024 * 1024; // [4][1024][1024]   (4M u)
    ushort* Qb  = Wt + 4ull * 1024 * 1024;  // [4096][1024]      (4M u)
    ushort* Kb  = Qb + 4ull * 1024 * 1024;  // [4096][1024]      (4M u)
    ushort* Vtb = Kb + 4ull * 1024 * 1024;  // [2][1024][2048]   (4M u)
    // After projections Xb is dead: Zinv (8M u) and Ob (4M u) alias it.
    ushort* Zinv = Xb;                       // [2][2048][2048] bf16 (8M u)
    ushort* Ob   = Xb + 8ull * 1024 * 1024;  // [4096][1024]        (4M u)

    convert_x_kernel<<<2048, 256, 0, stream>>>(queries, keys, values, Xb);
    transpose_w_kernel<<<dim3(16, 16, 4), 256, 0, stream>>>(Wq, Wk, Wv, Wo, Wt);
    proj_kernel<<<dim3(8, 32, 3), 256, 0, stream>>>(Xb, Wt, bq, bk, bv, Qb, Kb, Vtb);
    zsum_kernel<<<1024, 256, 0, stream>>>(Qb, Kb, Zinv);
    pv_kernel<<<512, 256, 0, stream>>>(Qb, Kb, Vtb, Zinv, Ob);
    outproj_kernel<<<dim3(8, 32), 256, 0, stream>>>(Ob, Wt + 3ull * 1024 * 1024, bo, out);
}